// Round 3
// baseline (640.288 us; speedup 1.0000x reference)
//
#include <hip/hip_runtime.h>
#include <math.h>

// QCQP via FISTA. One 512-thread workgroup per batch.
// R2 post-mortem: WRITE_SIZE 15.9MB (out=0.5MB) = scratch spills, caused by
// acc[16][2] (128 AGPR) + h[128] (128 VGPR) simultaneously live at remap
// under the launch_bounds reg cap of 256. TLP is structurally capped at
// 1 block/CU (one batch's H = half the CU register file), so this round
// attacks register pressure + the serial per-iteration chain:
//  - GEMM split into two row-passes (acc[8][2] = 64 AGPR, tiles 0-7 then
//    8-15, P re-staged) -> peak regs ~226 < 256, zero spills. Per-tile
//    MFMA accumulation order unchanged -> GEMM bit-identical.
//  - mv uses v_pk_fma_f32 (h reordered to h[4j+e], row-interleaved pairs):
//    64 packed FMAs instead of 128 scalar. Same accumulation order ->
//    bit-identical sums.
//  - projection: compare n2 > rr^2 (no sqrt) and scl = rr * rsqrtf(n2)
//    (1-ulp v_rsq) -> removes sqrt+div fixup chains from the serial path.
// Iteration scheme (readlane x-broadcast, 1 barrier/iter, ping-pong red)
// unchanged from the verified R2 kernel.

namespace {

constexpr int NDIM = 256;
constexpr int NCON = 128;
constexpr int PITERS = 20;
constexpr int FITERS = 100;

typedef short bf16x8 __attribute__((ext_vector_type(8)));
typedef float f32x4  __attribute__((ext_vector_type(4)));
typedef float f32x2  __attribute__((ext_vector_type(2)));

struct Smem {
    union {
        struct {                                 // GEMM phase only
            unsigned short fragHi[16 * 64 * 8];  // 16 KB
            unsigned short fragLo[16 * 64 * 8];  // 16 KB
        };
        float Hbuf[8][32 * 36];                  // 36.9 KB, remap scratch
    };
    float red[2][8][256];                        // 16 KB matvec partials, ping-pong
    float scal[16];
};                                               // ~53 KB

__device__ __forceinline__ unsigned short bf16rne(float x) {
    unsigned u = __float_as_uint(x);
    unsigned r = u + 0x7FFFu + ((u >> 16) & 1u);
    return (unsigned short)(r >> 16);
}

__device__ __forceinline__ float readlane_f(float v, int lane) {
    return __int_as_float(__builtin_amdgcn_readlane(__float_as_int(v), lane));
}

// pw = (partial H x)_{4l..4l+3} over this wave's 32 cols.
// h layout: h[4j+e] = H[4l+e][32w+j] (row-interleaved) so rows (e,e+1)
// sit in adjacent regs -> v_pk_fma_f32. x is wave-uniform (readlane).
// Accumulation order over j identical to the scalar version.
__device__ __forceinline__ void mv_pk(const float (&h)[128], const float (&xs)[32],
                                      float* __restrict__ redw, int l)
{
    const f32x2* h2 = (const f32x2*)h;
    f32x2 pw01 = {0.f, 0.f}, pw23 = {0.f, 0.f};
#pragma unroll
    for (int j = 0; j < 32; ++j) {
        f32x2 xb = {xs[j], xs[j]};
        pw01 = __builtin_elementwise_fma(h2[2 * j],     xb, pw01);
        pw23 = __builtin_elementwise_fma(h2[2 * j + 1], xb, pw23);
    }
    *(float4*)(redw + 4 * l) = make_float4(pw01.x, pw01.y, pw23.x, pw23.y);
}

// sum the 8 col-slice partials for rows (32w+2l, 32w+2l+1).
__device__ __forceinline__ float2 gather_pair(const float (*red8)[256], int w, int l)
{
    float s0 = 0.f, s1 = 0.f;
#pragma unroll
    for (int c2 = 0; c2 < 8; ++c2) {
        float2 p = *(const float2*)&red8[c2][32 * w + 2 * l];
        s0 += p.x; s1 += p.y;
    }
    return make_float2(s0, s1);
}

__global__ __launch_bounds__(512, 2)
void qcqp_fista(const float* __restrict__ P, const float* __restrict__ q,
                const float* __restrict__ ln_, const float* __restrict__ mu,
                float* __restrict__ out)
{
    __shared__ Smem sm;
    const int b = blockIdx.x;
    const int t = threadIdx.x;
    const int w = t >> 6;        // wave id = col block (cols 32w..32w+31)
    const int l = t & 63;

    const float* Pb = P + (size_t)b * (NDIM * NDIM);

    // ================== H = P^T P via bf16-split MFMA, TWO row-passes =====
    const int col  = t & 255;
    const int half = t >> 8;
    const int tile = col >> 4;

    float pf[16];
    auto load_chunk = [&](int cc) {
#pragma unroll
        for (int g = 0; g < 2; ++g) {
            const int qd = 2 * half + g;
            const float* src = Pb + (cc * 32 + qd * 8) * 256 + col;
#pragma unroll
            for (int j = 0; j < 8; ++j) pf[g * 8 + j] = src[j * 256];
        }
    };

    const int qd4 = (l >> 4) * 4;
    const int c16 = l & 15;
    float* Hw = sm.Hbuf[w];
    float h[128];

    load_chunk(0);
    for (int pass = 0; pass < 2; ++pass) {
        f32x4 acc[8][2];
#pragma unroll
        for (int i = 0; i < 8; ++i)
#pragma unroll
            for (int j = 0; j < 2; ++j)
#pragma unroll
                for (int e = 0; e < 4; ++e) acc[i][j][e] = 0.0f;

        for (int c = 0; c < 8; ++c) {
#pragma unroll
            for (int g = 0; g < 2; ++g) {
                const int qd = 2 * half + g;
                unsigned hw[4], lw[4];
#pragma unroll
                for (int jp = 0; jp < 4; ++jp) {
                    float f0 = pf[g * 8 + 2 * jp], f1 = pf[g * 8 + 2 * jp + 1];
                    unsigned short h0 = bf16rne(f0), h1 = bf16rne(f1);
                    float r0 = f0 - __uint_as_float((unsigned)h0 << 16);
                    float r1 = f1 - __uint_as_float((unsigned)h1 << 16);
                    unsigned short lo0 = bf16rne(r0), lo1 = bf16rne(r1);
                    hw[jp] = (unsigned)h0 | ((unsigned)h1 << 16);
                    lw[jp] = (unsigned)lo0 | ((unsigned)lo1 << 16);
                }
                const int slot = tile * 64 + ((col & 15) + 16 * qd);
                ((uint4*)sm.fragHi)[slot] = make_uint4(hw[0], hw[1], hw[2], hw[3]);
                ((uint4*)sm.fragLo)[slot] = make_uint4(lw[0], lw[1], lw[2], lw[3]);
            }
            __syncthreads();
            if (c < 7) load_chunk(c + 1);               // prefetch during MFMAs
            else if (pass == 0) load_chunk(0);          // re-stage for pass 2

            const bf16x8* FH = (const bf16x8*)sm.fragHi;
            const bf16x8* FL = (const bf16x8*)sm.fragLo;
            bf16x8 bh0 = FH[(2 * w) * 64 + l];
            bf16x8 bl0 = FL[(2 * w) * 64 + l];
            bf16x8 bh1 = FH[(2 * w + 1) * 64 + l];
            bf16x8 bl1 = FL[(2 * w + 1) * 64 + l];
#pragma unroll
            for (int tt = 0; tt < 8; ++tt) {
                bf16x8 ah = FH[(8 * pass + tt) * 64 + l];
                bf16x8 al = FL[(8 * pass + tt) * 64 + l];
                acc[tt][0] = __builtin_amdgcn_mfma_f32_16x16x32_bf16(ah, bh0, acc[tt][0], 0, 0, 0);
                acc[tt][0] = __builtin_amdgcn_mfma_f32_16x16x32_bf16(al, bh0, acc[tt][0], 0, 0, 0);
                acc[tt][0] = __builtin_amdgcn_mfma_f32_16x16x32_bf16(ah, bl0, acc[tt][0], 0, 0, 0);
                acc[tt][1] = __builtin_amdgcn_mfma_f32_16x16x32_bf16(ah, bh1, acc[tt][1], 0, 0, 0);
                acc[tt][1] = __builtin_amdgcn_mfma_f32_16x16x32_bf16(al, bh1, acc[tt][1], 0, 0, 0);
                acc[tt][1] = __builtin_amdgcn_mfma_f32_16x16x32_bf16(ah, bl1, acc[tt][1], 0, 0, 0);
            }
            __syncthreads();   // frag reads done before next writes / Hbuf reuse
        }

        // ---- remap this pass's 128 rows: acc -> h[4j+e] = H[4l+e][32w+j].
        //      Intra-wave LDS round trip; lanes 32*pass..32*pass+31 fill h.
#pragma unroll
        for (int rc = 0; rc < 4; ++rc) {        // local rows 32rc..32rc+31
#pragma unroll
            for (int s = 0; s < 2; ++s)
#pragma unroll
                for (int tc = 0; tc < 2; ++tc)
#pragma unroll
                    for (int reg = 0; reg < 4; ++reg)
                        Hw[(16 * s + qd4 + reg) * 36 + 16 * tc + c16] =
                            acc[2 * rc + s][tc][reg];
            if ((l >> 3) == 4 * pass + rc) {    // lanes owning these rows
                int l2 = l & 7;
#pragma unroll
                for (int e = 0; e < 4; ++e)
#pragma unroll
                    for (int jj = 0; jj < 8; ++jj) {
                        float4 v = *(const float4*)&Hw[(4 * l2 + e) * 36 + 4 * jj];
                        h[4 * (4 * jj + 0) + e] = v.x;
                        h[4 * (4 * jj + 1) + e] = v.y;
                        h[4 * (4 * jj + 2) + e] = v.z;
                        h[4 * (4 * jj + 3) + e] = v.w;
                    }
            }
        }
        if (pass == 0) __syncthreads();  // Hbuf aliases frag: guard pass-2 staging
    }

    // ================== power iteration ==================
    // lanes<16 hold the current y-slice (cols 32w+2l, +2l+1) in registers;
    // x broadcast wave-wide via readlane each iteration (no LDS reads).
    float cy0 = 1.0f, cy1 = 1.0f;
    int phase = 0;
    for (int it = 0; it < PITERS; ++it, ++phase) {
        float xs[32];
#pragma unroll
        for (int j = 0; j < 16; ++j) {
            xs[2 * j]     = readlane_f(cy0, j);
            xs[2 * j + 1] = readlane_f(cy1, j);
        }
        mv_pk(h, xs, sm.red[phase & 1][w], l);
        __syncthreads();
        if (l < 16) {
            float2 s = gather_pair(sm.red[phase & 1], w, l);
            cy0 = s.x * 0.0009765625f;
            cy1 = s.y * 0.0009765625f;
        }
    }

    // ---- Rayleigh quotient -> step ----
    {
        float xs[32];
#pragma unroll
        for (int j = 0; j < 16; ++j) {
            xs[2 * j]     = readlane_f(cy0, j);
            xs[2 * j + 1] = readlane_f(cy1, j);
        }
        mv_pk(h, xs, sm.red[phase & 1][w], l);
    }
    __syncthreads();
    float n1 = 0.f, n2 = 0.f;
    if (l < 16) {
        float2 hv = gather_pair(sm.red[phase & 1], w, l);
        n1 = cy0 * hv.x + cy1 * hv.y;
        n2 = cy0 * cy0 + cy1 * cy1;
    }
#pragma unroll
    for (int off = 1; off < 64; off <<= 1) {
        n1 += __shfl_xor(n1, off);
        n2 += __shfl_xor(n2, off);
    }
    if (l == 0) { sm.scal[w] = n1; sm.scal[8 + w] = n2; }
    __syncthreads();
    float num = 0.f, den = 0.f;
#pragma unroll
    for (int ww = 0; ww < 8; ++ww) { num += sm.scal[ww]; den += sm.scal[8 + ww]; }
    float L = num / den;
    const float step = 1.0f / (1.05f * fmaxf(L, 1e-12f));
    ++phase;

    // ================== FISTA ==================
    float b0 = 0.f, b1 = 0.f, rr = 0.f;
    if (l < 16) {
        float2 q2 = *(const float2*)(q + b * NDIM + 32 * w + 2 * l);
        b0 = q2.x; b1 = q2.y;
        rr = mu[b * NCON + 16 * w + l] * ln_[b * NCON + 16 * w + l];
    }
    const float rr2 = rr * rr;
    float li0 = 0.f, li1 = 0.f, tcur = 1.0f;
    cy0 = 0.0f; cy1 = 0.0f;                     // y0 = proj(0) = 0

    for (int it = 0; it < FITERS; ++it, ++phase) {
        float xs[32];
#pragma unroll
        for (int j = 0; j < 16; ++j) {
            xs[2 * j]     = readlane_f(cy0, j);
            xs[2 * j + 1] = readlane_f(cy1, j);
        }
        mv_pk(h, xs, sm.red[phase & 1][w], l);
        __syncthreads();
        float tn = 0.5f * (1.0f + sqrtf(1.0f + 4.0f * tcur * tcur));
        float ratio = (tcur - 1.0f) / tn;       // off the gather chain
        tcur = tn;
        if (l < 16) {
            float2 hy = gather_pair(sm.red[phase & 1], w, l);
            float z0 = cy0 - step * (hy.x + b0);
            float z1 = cy1 - step * (hy.y + b1);
            float n2sq = z0 * z0 + z1 * z1;
            // nrm > rr  <=>  n2sq > rr^2 (rr >= 0); scl via 1-ulp HW rsqrt
            float scl = (n2sq > rr2) ? (rr * rsqrtf(n2sq)) : 1.0f;
            float l0 = z0 * scl, l1 = z1 * scl;
            float yn0 = l0 + ratio * (l0 - li0);
            float yn1 = l1 + ratio * (l1 - li1);
            li0 = l0; li1 = l1;
            cy0 = yn0; cy1 = yn1;
        }
    }

    if (l < 16)
        *(float2*)(out + b * NDIM + 32 * w + 2 * l) = make_float2(li0, li1);
}

} // namespace

extern "C" void kernel_launch(void* const* d_in, const int* in_sizes, int n_in,
                              void* d_out, int out_size, void* d_ws, size_t ws_size,
                              hipStream_t stream) {
    const float* P   = (const float*)d_in[0];
    const float* q   = (const float*)d_in[1];
    const float* l_n = (const float*)d_in[2];
    const float* mu  = (const float*)d_in[3];
    float* out = (float*)d_out;
    qcqp_fista<<<dim3(512), dim3(512), 0, stream>>>(P, q, l_n, mu, out);
}

// Round 4
// 384.022 us; speedup vs baseline: 1.6673x; 1.6673x over previous
//
#include <hip/hip_runtime.h>
#include <math.h>

// QCQP via FISTA. One 512-thread workgroup per batch.
// R3 post-mortem: two-pass GEMM made h[128] live across a whole GEMM pass
// -> full scratch spill (WRITE 326MB) -> 535us. Reverted to the verified
// R2 single-pass GEMM + per-rc remap (acc dies as h is born, 32 rows at a
// time -> peak ~240 regs, ~15-reg spill only). Kept from R3 (numerics
// verified bit-identical there): interleaved h[4j+e] + v_pk_fma_f32 mv
// (halves mv issue), rsqrt projection (no sqrt/div on serial chain).
// New: 32-lane update - lanes 0..31 own ONE y component each (was 16
// lanes owning pairs): halves the readlane broadcast (64->32/iter);
// pair norm via one shfl_xor. Iteration scheme otherwise unchanged:
// readlane x-broadcast, 1 barrier/iter, ping-pong red buffers.

namespace {

constexpr int NDIM = 256;
constexpr int NCON = 128;
constexpr int PITERS = 20;
constexpr int FITERS = 100;

typedef short bf16x8 __attribute__((ext_vector_type(8)));
typedef float f32x4  __attribute__((ext_vector_type(4)));
typedef float f32x2  __attribute__((ext_vector_type(2)));

struct Smem {
    union {
        struct {                                 // GEMM phase only
            unsigned short fragHi[16 * 64 * 8];  // 16 KB
            unsigned short fragLo[16 * 64 * 8];  // 16 KB
        };
        float Hbuf[8][32 * 36];                  // 36.9 KB, remap scratch
    };
    float red[2][8][256];                        // 16 KB matvec partials, ping-pong
    float scal[16];
};                                               // ~53 KB

__device__ __forceinline__ unsigned short bf16rne(float x) {
    unsigned u = __float_as_uint(x);
    unsigned r = u + 0x7FFFu + ((u >> 16) & 1u);
    return (unsigned short)(r >> 16);
}

__device__ __forceinline__ float readlane_f(float v, int lane) {
    return __int_as_float(__builtin_amdgcn_readlane(__float_as_int(v), lane));
}

// pw = (partial H x)_{4l..4l+3} over this wave's 32 cols.
// h layout: h[4j+e] = H[4l+e][32w+j] (row-interleaved) so rows (0,1) and
// (2,3) sit in adjacent regs -> v_pk_fma_f32. x comes from lanes 0..31's
// cy via readlane (broadcast, no LDS). Accumulation order over j identical
// to the verified scalar version -> bit-identical sums.
__device__ __forceinline__ void mv_pk(const float (&h)[128], float cy,
                                      float* __restrict__ redw, int l)
{
    const f32x2* h2 = (const f32x2*)h;
    f32x2 pw01 = {0.f, 0.f}, pw23 = {0.f, 0.f};
#pragma unroll
    for (int j = 0; j < 32; ++j) {
        float x = readlane_f(cy, j);
        f32x2 xb = {x, x};
        pw01 = __builtin_elementwise_fma(h2[2 * j],     xb, pw01);
        pw23 = __builtin_elementwise_fma(h2[2 * j + 1], xb, pw23);
    }
    *(float4*)(redw + 4 * l) = make_float4(pw01.x, pw01.y, pw23.x, pw23.y);
}

// sum the 8 col-slice partials for row 32w+l (lane l < 32).
__device__ __forceinline__ float gather_one(const float (*red8)[256], int w, int l)
{
    const float* rp = &red8[0][32 * w + l];
    float s = 0.f;
#pragma unroll
    for (int c = 0; c < 8; ++c) s += rp[c * 256];
    return s;
}

__global__ __launch_bounds__(512, 2)
void qcqp_fista(const float* __restrict__ P, const float* __restrict__ q,
                const float* __restrict__ ln_, const float* __restrict__ mu,
                float* __restrict__ out)
{
    __shared__ Smem sm;
    const int b = blockIdx.x;
    const int t = threadIdx.x;
    const int w = t >> 6;        // wave id = col block (cols 32w..32w+31)
    const int l = t & 63;

    const float* Pb = P + (size_t)b * (NDIM * NDIM);

    // ================== H = P^T P via bf16-split MFMA (R2-verbatim) ======
    const int col  = t & 255;
    const int half = t >> 8;
    const int tile = col >> 4;

    float pf[16];
    auto load_chunk = [&](int cc) {
#pragma unroll
        for (int g = 0; g < 2; ++g) {
            const int qd = 2 * half + g;
            const float* src = Pb + (cc * 32 + qd * 8) * 256 + col;
#pragma unroll
            for (int j = 0; j < 8; ++j) pf[g * 8 + j] = src[j * 256];
        }
    };

    f32x4 acc[16][2];
#pragma unroll
    for (int i = 0; i < 16; ++i)
#pragma unroll
        for (int j = 0; j < 2; ++j)
#pragma unroll
            for (int e = 0; e < 4; ++e) acc[i][j][e] = 0.0f;

    load_chunk(0);
    for (int c = 0; c < 8; ++c) {
#pragma unroll
        for (int g = 0; g < 2; ++g) {
            const int qd = 2 * half + g;
            unsigned hw[4], lw[4];
#pragma unroll
            for (int jp = 0; jp < 4; ++jp) {
                float f0 = pf[g * 8 + 2 * jp], f1 = pf[g * 8 + 2 * jp + 1];
                unsigned short h0 = bf16rne(f0), h1 = bf16rne(f1);
                float r0 = f0 - __uint_as_float((unsigned)h0 << 16);
                float r1 = f1 - __uint_as_float((unsigned)h1 << 16);
                unsigned short lo0 = bf16rne(r0), lo1 = bf16rne(r1);
                hw[jp] = (unsigned)h0 | ((unsigned)h1 << 16);
                lw[jp] = (unsigned)lo0 | ((unsigned)lo1 << 16);
            }
            const int slot = tile * 64 + ((col & 15) + 16 * qd);
            ((uint4*)sm.fragHi)[slot] = make_uint4(hw[0], hw[1], hw[2], hw[3]);
            ((uint4*)sm.fragLo)[slot] = make_uint4(lw[0], lw[1], lw[2], lw[3]);
        }
        __syncthreads();
        if (c < 7) load_chunk(c + 1);          // prefetch during MFMAs

        const bf16x8* FH = (const bf16x8*)sm.fragHi;
        const bf16x8* FL = (const bf16x8*)sm.fragLo;
        bf16x8 bh0 = FH[(2 * w) * 64 + l];
        bf16x8 bl0 = FL[(2 * w) * 64 + l];
        bf16x8 bh1 = FH[(2 * w + 1) * 64 + l];
        bf16x8 bl1 = FL[(2 * w + 1) * 64 + l];
#pragma unroll
        for (int tr = 0; tr < 16; ++tr) {
            bf16x8 ah = FH[tr * 64 + l];
            bf16x8 al = FL[tr * 64 + l];
            acc[tr][0] = __builtin_amdgcn_mfma_f32_16x16x32_bf16(ah, bh0, acc[tr][0], 0, 0, 0);
            acc[tr][0] = __builtin_amdgcn_mfma_f32_16x16x32_bf16(al, bh0, acc[tr][0], 0, 0, 0);
            acc[tr][0] = __builtin_amdgcn_mfma_f32_16x16x32_bf16(ah, bl0, acc[tr][0], 0, 0, 0);
            acc[tr][1] = __builtin_amdgcn_mfma_f32_16x16x32_bf16(ah, bh1, acc[tr][1], 0, 0, 0);
            acc[tr][1] = __builtin_amdgcn_mfma_f32_16x16x32_bf16(al, bh1, acc[tr][1], 0, 0, 0);
            acc[tr][1] = __builtin_amdgcn_mfma_f32_16x16x32_bf16(ah, bl1, acc[tr][1], 0, 0, 0);
        }
        __syncthreads();   // all frag reads done before next writes / Hbuf reuse
    }

    // ---- acc (C layout: row=16tr+4q+reg, col=16(2w+tc)+c16) -> mv layout
    //      h[4j+e] = H[4l+e][32w+j] (interleaved for pk-fma). Per-rc:
    //      acc rows die as h fills -> peak regs ~240. Intra-wave LDS round
    //      trip (same-wave LDS ops are ordered, no barrier). ----
    const int qd4 = (l >> 4) * 4;
    const int c16 = l & 15;
    float* Hw = sm.Hbuf[w];
    float h[128];
#pragma unroll
    for (int rc = 0; rc < 8; ++rc) {           // rows 32rc..32rc+31
#pragma unroll
        for (int tt = 0; tt < 2; ++tt)
#pragma unroll
            for (int tc = 0; tc < 2; ++tc)
#pragma unroll
                for (int reg = 0; reg < 4; ++reg) {
                    int row_local = 16 * tt + qd4 + reg;
                    Hw[row_local * 36 + 16 * tc + c16] = acc[2 * rc + tt][tc][reg];
                }
        if ((l >> 3) == rc) {                   // lanes 8rc..8rc+7
            int l2 = l & 7;
#pragma unroll
            for (int e = 0; e < 4; ++e)
#pragma unroll
                for (int jj = 0; jj < 8; ++jj) {
                    float4 v = *(const float4*)&Hw[(4 * l2 + e) * 36 + 4 * jj];
                    h[4 * (4 * jj + 0) + e] = v.x;
                    h[4 * (4 * jj + 1) + e] = v.y;
                    h[4 * (4 * jj + 2) + e] = v.z;
                    h[4 * (4 * jj + 3) + e] = v.w;
                }
        }
    }

    // ================== power iteration ==================
    // lanes 0..31 hold y component 32w+l in cy; x broadcast via readlane.
    float cy = 1.0f;
    int phase = 0;
    for (int it = 0; it < PITERS; ++it, ++phase) {
        mv_pk(h, cy, sm.red[phase & 1][w], l);
        __syncthreads();
        if (l < 32) {
            float s = gather_one(sm.red[phase & 1], w, l);
            cy = s * 0.0009765625f;
        }
    }

    // ---- Rayleigh quotient -> step ----
    mv_pk(h, cy, sm.red[phase & 1][w], l);
    __syncthreads();
    float n1 = 0.f, n2 = 0.f;
    if (l < 32) {
        float hv = gather_one(sm.red[phase & 1], w, l);
        n1 = cy * hv;
        n2 = cy * cy;
    }
#pragma unroll
    for (int off = 1; off < 64; off <<= 1) {
        n1 += __shfl_xor(n1, off);
        n2 += __shfl_xor(n2, off);
    }
    if (l == 0) { sm.scal[w] = n1; sm.scal[8 + w] = n2; }
    __syncthreads();
    float num = 0.f, den = 0.f;
#pragma unroll
    for (int ww = 0; ww < 8; ++ww) { num += sm.scal[ww]; den += sm.scal[8 + ww]; }
    float L = num / den;
    const float step = 1.0f / (1.05f * fmaxf(L, 1e-12f));
    ++phase;

    // ================== FISTA ==================
    float bq = 0.f, rrv = 0.f, rr2 = 0.f;
    if (l < 32) {
        bq = q[b * NDIM + 32 * w + l];
        float rv = mu[b * NCON + 16 * w + (l >> 1)] * ln_[b * NCON + 16 * w + (l >> 1)];
        rrv = rv;
        rr2 = rv * rv;
    }
    float li = 0.f, tcur = 1.0f;
    cy = 0.0f;                                  // y0 = proj(0) = 0

    for (int it = 0; it < FITERS; ++it, ++phase) {
        mv_pk(h, cy, sm.red[phase & 1][w], l);
        __syncthreads();
        float tn = 0.5f * (1.0f + sqrtf(1.0f + 4.0f * tcur * tcur));
        float ratio = (tcur - 1.0f) / tn;       // off the gather chain
        tcur = tn;
        if (l < 32) {
            float hy = gather_one(sm.red[phase & 1], w, l);
            float z  = cy - step * (hy + bq);
            float zz = z * z;
            float n2p = zz + __shfl_xor(zz, 1);  // pair (2p,2p+1) norm^2
            // nrm > rr  <=>  n2p > rr^2 (rr >= 0); scl via 1-ulp HW rsqrt
            float scl = (n2p > rr2) ? (rrv * rsqrtf(n2p)) : 1.0f;
            float l0 = z * scl;
            float yn = l0 + ratio * (l0 - li);
            li = l0;
            cy = yn;
        }
    }

    if (l < 32)
        out[b * NDIM + 32 * w + l] = li;
}

} // namespace

extern "C" void kernel_launch(void* const* d_in, const int* in_sizes, int n_in,
                              void* d_out, int out_size, void* d_ws, size_t ws_size,
                              hipStream_t stream) {
    const float* P   = (const float*)d_in[0];
    const float* q   = (const float*)d_in[1];
    const float* l_n = (const float*)d_in[2];
    const float* mu  = (const float*)d_in[3];
    float* out = (float*)d_out;
    qcqp_fista<<<dim3(512), dim3(512), 0, stream>>>(P, q, l_n, mu, out);
}